// Round 5
// baseline (140.180 us; speedup 1.0000x reference)
//
#include <hip/hip_runtime.h>
#include <math.h>

// Problem constants (fixed by the reference).
#define TOK   16
#define TOPA  2
#define NPAIR (TOK * TOPA)   // 32
#define DIM   1024
#define INTER 2816
#define NEXP  8

// Build a uniform 32-bit mask of pairs routed to expert e (lands in SGPRs).
__device__ __forceinline__ unsigned pair_mask(const int* __restrict__ eidx, int e) {
    unsigned mask = 0;
    #pragma unroll
    for (int k = 0; k < NPAIR / 4; ++k) {
        const int4 v = ((const int4*)eidx)[k];
        mask |= (unsigned)(v.x == e) << (4 * k + 0);
        mask |= (unsigned)(v.y == e) << (4 * k + 1);
        mask |= (unsigned)(v.z == e) << (4 * k + 2);
        mask |= (unsigned)(v.w == e) << (4 * k + 3);
    }
    return mask;
}

__device__ __forceinline__ float dot4(float4 a, float4 b) {
    return a.x * b.x + a.y * b.y + a.z * b.z + a.w * b.w;
}

// ---------------------------------------------------------------------------
// Kernel 1: h[p][o] = silu(x[t].w1[e][o]) * (x[t].w3[e][o])
// 4-lane row groups: g = lane>>2 (16 groups), i = lane&3.
// Groups 0-7  -> rows r0..r0+7 of w1; groups 8-15 -> same rows of w3.
// Lane i reads float4 index k*4+i of its row: per wave-load, 16 segments of
// 64 B, each a fully-consumed cache line. Loads flow every k iteration.
// Reduce: 2 butterfly levels in the quad + 1 shfl_xor(32) to pair w1/w3.
// Wave = 8 rows (both mats); block = 32 rows; grid (INTER/32, NEXP).
// ---------------------------------------------------------------------------
__global__ __launch_bounds__(256) void moe_gate_up(
    const float* __restrict__ x,     // [TOK][DIM]
    const int*   __restrict__ eidx,  // [TOK][TOPA]
    const float* __restrict__ w1,    // [NEXP][INTER][DIM]
    const float* __restrict__ w3,    // [NEXP][INTER][DIM]
    float*       __restrict__ h)     // [NPAIR][INTER]
{
    const int e = blockIdx.y;
    unsigned mask = pair_mask(eidx, e);
    if (!mask) return;   // skip this expert's weights entirely

    const int tid  = threadIdx.x;
    const int lane = tid & 63;
    const int wave = tid >> 6;
    const int g    = lane >> 2;        // 0..15
    const int i    = lane & 3;         // 0..3
    const int mat  = g >> 3;           // 0 -> w1, 1 -> w3
    const int row  = blockIdx.x * 32 + wave * 8 + (g & 7);

    const float* wsel = mat ? w3 : w1;
    const float4* wp = (const float4*)(wsel + ((size_t)e * INTER + row) * DIM) + i;
    const float4* xb = (const float4*)x + i;

    while (mask) {
        // Pull up to 4 pairs (pad with duplicates of p0; writes guarded by nv).
        int p0 = __builtin_ctz(mask); mask &= mask - 1;
        int p1 = p0, p2 = p0, p3 = p0, nv = 1;
        if (mask) { p1 = __builtin_ctz(mask); mask &= mask - 1; nv = 2;
        if (mask) { p2 = __builtin_ctz(mask); mask &= mask - 1; nv = 3;
        if (mask) { p3 = __builtin_ctz(mask); mask &= mask - 1; nv = 4; } } }

        const float4* x0 = xb + (size_t)(p0 >> 1) * (DIM / 4);
        const float4* x1 = xb + (size_t)(p1 >> 1) * (DIM / 4);
        const float4* x2 = xb + (size_t)(p2 >> 1) * (DIM / 4);
        const float4* x3 = xb + (size_t)(p3 >> 1) * (DIM / 4);

        float a0 = 0.f, a1 = 0.f, a2 = 0.f, a3 = 0.f;

        #pragma unroll 4
        for (int k = 0; k < 64; ++k) {
            const float4 w  = wp[k * 4];
            const float4 v0 = x0[k * 4];
            const float4 v1 = x1[k * 4];
            const float4 v2 = x2[k * 4];
            const float4 v3 = x3[k * 4];
            a0 += dot4(w, v0);
            a1 += dot4(w, v1);
            a2 += dot4(w, v2);
            a3 += dot4(w, v3);
        }

        // Reduce within the 4-lane quad: 2 levels, 4 independent chains.
        #pragma unroll
        for (int off = 1; off < 4; off <<= 1) {
            a0 += __shfl_xor(a0, off);
            a1 += __shfl_xor(a1, off);
            a2 += __shfl_xor(a2, off);
            a3 += __shfl_xor(a3, off);
        }

        // Pair w1-lane with its w3-partner (lane ^ 32: same row, same quad slot).
        const float b0 = __shfl_xor(a0, 32);
        const float b1 = __shfl_xor(a1, 32);
        const float b2 = __shfl_xor(a2, 32);
        const float b3 = __shfl_xor(a3, 32);

        // Lanes of mat==0 write: quad slot i selects pair i. 32 lanes store
        // 4 pairs x 8 rows in one instruction.
        if (mat == 0 && i < nv) {
            const float s1v = (i == 0) ? a0 : (i == 1) ? a1 : (i == 2) ? a2 : a3;
            const float s3v = (i == 0) ? b0 : (i == 1) ? b1 : (i == 2) ? b2 : b3;
            const int   ps  = (i == 0) ? p0 : (i == 1) ? p1 : (i == 2) ? p2 : p3;
            const float gv  = s1v / (1.f + __expf(-s1v));   // silu
            h[(size_t)ps * INTER + row] = gv * s3v;
        }
    }
}

// ---------------------------------------------------------------------------
// Kernel 2: out[p][d] = sum_o h[p][o] * w2[e][d][o]
// 16-lane row groups: g = lane>>4 (4 groups = 4 rows/wave), i = lane&15.
// Lane i reads float4 index k*16+i (k = 0..43; 44*16 = 704 = INTER/4).
// Per wave-load: 4 segments of 256 B, fully consumed. Reduce: 4 levels.
// Wave = 4 rows; block = 16 rows; grid (DIM/16, NEXP) = 512 blocks.
// ---------------------------------------------------------------------------
__global__ __launch_bounds__(256) void moe_down(
    const float* __restrict__ h,     // [NPAIR][INTER]
    const int*   __restrict__ eidx,  // [TOK][TOPA]
    const float* __restrict__ w2,    // [NEXP][DIM][INTER]
    float*       __restrict__ out)   // [NPAIR][DIM]
{
    const int e = blockIdx.y;
    unsigned mask = pair_mask(eidx, e);
    if (!mask) return;

    const int tid  = threadIdx.x;
    const int lane = tid & 63;
    const int wave = tid >> 6;
    const int g    = lane >> 4;        // 0..3
    const int i    = lane & 15;        // 0..15
    const int row  = blockIdx.x * 16 + wave * 4 + g;

    const float4* wp = (const float4*)(w2 + ((size_t)e * DIM + row) * INTER) + i;
    const float4* hb = (const float4*)h + i;

    while (mask) {
        int p0 = __builtin_ctz(mask); mask &= mask - 1;
        int p1 = p0, p2 = p0, p3 = p0, nv = 1;
        if (mask) { p1 = __builtin_ctz(mask); mask &= mask - 1; nv = 2;
        if (mask) { p2 = __builtin_ctz(mask); mask &= mask - 1; nv = 3;
        if (mask) { p3 = __builtin_ctz(mask); mask &= mask - 1; nv = 4; } } }

        const float4* h0 = hb + (size_t)p0 * (INTER / 4);
        const float4* h1 = hb + (size_t)p1 * (INTER / 4);
        const float4* h2 = hb + (size_t)p2 * (INTER / 4);
        const float4* h3 = hb + (size_t)p3 * (INTER / 4);

        float a0 = 0.f, a1 = 0.f, a2 = 0.f, a3 = 0.f;

        #pragma unroll 4
        for (int k = 0; k < 44; ++k) {
            const float4 w  = wp[k * 16];
            const float4 v0 = h0[k * 16];
            const float4 v1 = h1[k * 16];
            const float4 v2 = h2[k * 16];
            const float4 v3 = h3[k * 16];
            a0 += dot4(w, v0);
            a1 += dot4(w, v1);
            a2 += dot4(w, v2);
            a3 += dot4(w, v3);
        }

        // Reduce within the 16-lane group: 4 levels, 4 independent chains.
        #pragma unroll
        for (int off = 1; off < 16; off <<= 1) {
            a0 += __shfl_xor(a0, off);
            a1 += __shfl_xor(a1, off);
            a2 += __shfl_xor(a2, off);
            a3 += __shfl_xor(a3, off);
        }

        // Group slot i selects pair i: up to 16 lanes store 4 pairs x 4 rows.
        if (i < nv) {
            const float sv = (i == 0) ? a0 : (i == 1) ? a1 : (i == 2) ? a2 : a3;
            const int   ps = (i == 0) ? p0 : (i == 1) ? p1 : (i == 2) ? p2 : p3;
            out[(size_t)ps * DIM + row] = sv;
        }
    }
}

// ---------------------------------------------------------------------------
extern "C" void kernel_launch(void* const* d_in, const int* in_sizes, int n_in,
                              void* d_out, int out_size, void* d_ws, size_t ws_size,
                              hipStream_t stream) {
    const float* x    = (const float*)d_in[0];
    const int*   eidx = (const int*)  d_in[1];
    const float* w1   = (const float*)d_in[2];
    const float* w2   = (const float*)d_in[3];
    const float* w3   = (const float*)d_in[4];
    float* out = (float*)d_out;
    float* hws = (float*)d_ws;   // [NPAIR][INTER] f32 = 360448 B

    dim3 g1(INTER / 32, NEXP);   // 88 x 8 blocks; wave = 8 rows of w1+w3
    moe_gate_up<<<g1, 256, 0, stream>>>(x, eidx, w1, w3, hws);

    dim3 g2(DIM / 16, NEXP);     // 64 x 8 blocks; wave = 4 rows of w2
    moe_down<<<g2, 256, 0, stream>>>(hws, eidx, w2, out);
}

// Round 7
// 79.907 us; speedup vs baseline: 1.7543x; 1.7543x over previous
//
#include <hip/hip_runtime.h>
#include <math.h>
#include <stdint.h>

// Problem constants (fixed by the reference).
#define TOK   16
#define TOPA  2
#define NPAIR 32
#define DIM   1024
#define INTER 2816
#define NEXP  8

// Gate kernel tiling: 32 output rows per block (x2 matrices), K-chunks of 64.
#define KC1   64
#define NC1   16      // DIM / KC1
#define GROWS 32
// Down kernel tiling: 16 output rows per block, K-chunks of 128.
#define KC2   128
#define NC2   22      // INTER / KC2
#define DROWS 16

#define WAITV(n) asm volatile("s_waitcnt vmcnt(" #n ")" ::: "memory")
#define BARR()   do { __builtin_amdgcn_s_barrier(); __builtin_amdgcn_sched_barrier(0); } while (0)

__device__ __forceinline__ float dot4(float4 a, float4 b) {
    return a.x * b.x + a.y * b.y + a.z * b.z + a.w * b.w;
}

// Async global->LDS, 16B per lane. LDS dest must be linear (base + lane*16).
// Address-space casts must go through uintptr_t (direct ptr->AS ptr casts
// are rejected by clang).
__device__ __forceinline__ void gload16(const float* g, float* l) {
    auto gp = reinterpret_cast<const __attribute__((address_space(1))) uint32_t*>(
                  reinterpret_cast<uintptr_t>(g));
    auto lp = reinterpret_cast<__attribute__((address_space(3))) uint32_t*>(
                  reinterpret_cast<uintptr_t>(l));
    __builtin_amdgcn_global_load_lds(gp, lp, 16, 0, 0);
}

// Uniform 32-bit mask of pairs routed to expert e (scalar, lands in SGPRs).
__device__ __forceinline__ unsigned pair_mask(const int* __restrict__ eidx, int e) {
    unsigned mask = 0;
    #pragma unroll
    for (int k = 0; k < NPAIR / 4; ++k) {
        const int4 v = ((const int4*)eidx)[k];
        mask |= (unsigned)(v.x == e) << (4 * k + 0);
        mask |= (unsigned)(v.y == e) << (4 * k + 1);
        mask |= (unsigned)(v.z == e) << (4 * k + 2);
        mask |= (unsigned)(v.w == e) << (4 * k + 3);
    }
    return mask;
}

// ---------------------------------------------------------------------------
// Gate group body: h[p][o] = silu(x.w1[o]) * (x.w3[o]) for up to JMAX pairs.
// LDS w-tile [64][64] f32 (rows interleaved w1/w3), XOR-swizzled columns:
// quad col' = q16 ^ (trow&7). x-tile [16][64] linear.
// Thread role: q2 = tid&3 (k-split, 4 quads each), trow = tid>>2,
// mt = trow&1 (0=w1,1=w3), row = trow>>1 (0..31).
// Per thread: full-k partial dot in registers; ONE 2-level butterfly +
// one mat-partner shuffle at the end. No shuffles in the chunk loop.
// ---------------------------------------------------------------------------
template <int JMAX>
__device__ __forceinline__ void gate_group(
    const float* __restrict__ w1, const float* __restrict__ w3,
    const float* __restrict__ x,  float* __restrict__ hout,
    float* wb0, float* wb1, float* xb0, float* xb1,
    int e, int r0, int tid, const int (&pj)[8], int npg)
{
    const int q2   = tid & 3;
    const int trow = tid >> 2;
    const int mt   = trow & 1;
    const int row  = trow >> 1;

    // Staging sources: 4 w-issues (64 rows x 16 quads) + 1 x-issue per chunk.
    // flat = q*256+tid: strow = flat>>4, swizzled col = (flat&15) ^ (strow&7).
    const float* wsrc[4];
    #pragma unroll
    for (int q = 0; q < 4; ++q) {
        const int flat  = q * 256 + tid;
        const int strow = flat >> 4;
        const int scol  = (flat & 15) ^ (strow & 7);
        const float* wbase = (strow & 1) ? w3 : w1;
        wsrc[q] = wbase + ((size_t)e * INTER + r0 + (strow >> 1)) * DIM + scol * 4;
    }
    const float* xsrc = x + (size_t)(tid >> 4) * DIM + (tid & 15) * 4;

    int tb[JMAX];
    #pragma unroll
    for (int j = 0; j < JMAX; ++j) tb[j] = (pj[j] >> 1) * KC1;

    float acc[JMAX];
    #pragma unroll
    for (int j = 0; j < JMAX; ++j) acc[j] = 0.f;

    auto stage = [&](int kc, float* wb, float* xb) {
        const int ko = kc * KC1;
        #pragma unroll
        for (int q = 0; q < 4; ++q)
            gload16(wsrc[q] + ko, wb + q * 1024 + tid * 4);
        gload16(xsrc + ko, xb + tid * 4);
    };
    auto compute = [&](const float* wb, const float* xb) {
        #pragma unroll
        for (int kq = 0; kq < 4; ++kq) {
            const int q16 = (q2 << 2) | kq;
            const float4 w4 =
                *(const float4*)(wb + trow * KC1 + ((q16 ^ (trow & 7)) << 2));
            #pragma unroll
            for (int j = 0; j < JMAX; ++j) {
                const float4 xv = *(const float4*)(xb + tb[j] + (q16 << 2));
                acc[j] += dot4(w4, xv);
            }
        }
    };

    // 2-phase pipeline, counted vmcnt (5 issues/chunk stay in flight).
    stage(0, wb0, xb0);
    #pragma unroll 1
    for (int c = 0; c < NC1; c += 2) {
        stage(c + 1, wb1, xb1);
        WAITV(5);
        BARR();
        compute(wb0, xb0);
        BARR();
        if (c + 2 < NC1) { stage(c + 2, wb0, xb0); WAITV(5); }
        else             { WAITV(0); }
        BARR();
        compute(wb1, xb1);
        BARR();
    }

    // Reduce k-split (2 levels), fetch w3 partner (xor 4), store.
    #pragma unroll
    for (int j = 0; j < JMAX; ++j) {
        float s = acc[j];
        s += __shfl_xor(s, 1);
        s += __shfl_xor(s, 2);
        const float part = __shfl_xor(s, 4);   // other matrix, same row
        if (mt == 0 && (j & 3) == q2 && j < npg) {
            const float g = s / (1.f + __expf(-s));   // silu(x.w1)
            hout[(size_t)pj[j] * INTER + r0 + row] = g * part;
        }
    }
}

__global__ __launch_bounds__(256) void moe_gate_up(
    const float* __restrict__ x,  const int* __restrict__ eidx,
    const float* __restrict__ w1, const float* __restrict__ w3,
    float* __restrict__ hout)
{
    __shared__ float wb0[4096], wb1[4096];   // [64][64] f32 each
    __shared__ float xb0[1024], xb1[1024];   // [16][64] f32 each

    const int e = blockIdx.y;
    unsigned mrem = pair_mask(eidx, e);
    if (!mrem) return;   // skip this expert's weights entirely

    const int tid = threadIdx.x;
    const int r0  = blockIdx.x * GROWS;

    while (mrem) {
        int pj[8];
        const int pfirst = __builtin_ctz(mrem);
        unsigned mg = mrem;
        int npg = 0;
        #pragma unroll
        for (int j = 0; j < 8; ++j) {
            if (mg) { pj[j] = __builtin_ctz(mg); mg &= mg - 1; ++npg; }
            else    { pj[j] = pfirst; }
        }
        mrem = mg;
        if (npg > 4) gate_group<8>(w1, w3, x, hout, wb0, wb1, xb0, xb1, e, r0, tid, pj, npg);
        else         gate_group<4>(w1, w3, x, hout, wb0, wb1, xb0, xb1, e, r0, tid, pj, npg);
    }
}

// ---------------------------------------------------------------------------
// Down group body: out[p][d] = sum_o h[p][o] * w2[e][d][o].
// LDS w2-tile [16][128] f32 XOR-swizzled; h-tile [8][128] linear (only the
// matched pairs' rows are staged). Thread: sub = tid&15 (k-split, 2 quads),
// slot = tid>>4 (row 0..15). 4-level butterfly once at the end.
// ---------------------------------------------------------------------------
template <int JMAX>
__device__ __forceinline__ void down_group(
    const float* __restrict__ hsrcbase, const float* __restrict__ w2,
    float* __restrict__ outp,
    float* wb0, float* wb1, float* hb0, float* hb1,
    int e, int r0, int tid, const int (&pj)[8], int npg)
{
    const int sub  = tid & 15;
    const int slot = tid >> 4;

    const float* wsrc[2];
    #pragma unroll
    for (int q = 0; q < 2; ++q) {
        const int flat  = q * 256 + tid;
        const int strow = flat >> 5;
        const int scol  = (flat & 31) ^ (strow & 7);
        wsrc[q] = w2 + ((size_t)e * DIM + r0 + strow) * INTER + scol * 4;
    }
    // h staging: row tid>>5 holds pair pj[tid>>5] (static select, rule #20).
    const int hr = tid >> 5;
    int hp = pj[0];
    #pragma unroll
    for (int j = 1; j < 8; ++j) if (hr == j) hp = pj[j];
    const float* hsrc = hsrcbase + (size_t)hp * INTER + (tid & 31) * 4;

    float acc[JMAX];
    #pragma unroll
    for (int j = 0; j < JMAX; ++j) acc[j] = 0.f;

    auto stage = [&](int kc, float* wb, float* hb) {
        const int ko = kc * KC2;
        gload16(wsrc[0] + ko, wb + tid * 4);
        gload16(wsrc[1] + ko, wb + 1024 + tid * 4);
        gload16(hsrc + ko, hb + tid * 4);
    };
    auto compute = [&](const float* wb, const float* hb) {
        #pragma unroll
        for (int qq = 0; qq < 2; ++qq) {
            const int q32 = (sub << 1) | qq;
            const float4 w4 =
                *(const float4*)(wb + slot * KC2 + ((q32 ^ (slot & 7)) << 2));
            #pragma unroll
            for (int j = 0; j < JMAX; ++j) {
                const float4 hv = *(const float4*)(hb + j * KC2 + (q32 << 2));
                acc[j] += dot4(w4, hv);
            }
        }
    };

    stage(0, wb0, hb0);
    #pragma unroll 1
    for (int c = 0; c < NC2; c += 2) {
        stage(c + 1, wb1, hb1);
        WAITV(3);
        BARR();
        compute(wb0, hb0);
        BARR();
        if (c + 2 < NC2) { stage(c + 2, wb0, hb0); WAITV(3); }
        else             { WAITV(0); }
        BARR();
        compute(wb1, hb1);
        BARR();
    }

    #pragma unroll
    for (int j = 0; j < JMAX; ++j) {
        float s = acc[j];
        s += __shfl_xor(s, 1);
        s += __shfl_xor(s, 2);
        s += __shfl_xor(s, 4);
        s += __shfl_xor(s, 8);
        if (sub == j && j < npg)
            outp[(size_t)pj[j] * DIM + r0 + slot] = s;
    }
}

__global__ __launch_bounds__(256) void moe_down(
    const float* __restrict__ h, const int* __restrict__ eidx,
    const float* __restrict__ w2, float* __restrict__ outp)
{
    __shared__ float wb0[2048], wb1[2048];   // [16][128] f32 each
    __shared__ float hb0[1024], hb1[1024];   // [8][128] f32 each

    const int e = blockIdx.y;
    unsigned mrem = pair_mask(eidx, e);
    if (!mrem) return;

    const int tid = threadIdx.x;
    const int r0  = blockIdx.x * DROWS;

    while (mrem) {
        int pj[8];
        const int pfirst = __builtin_ctz(mrem);
        unsigned mg = mrem;
        int npg = 0;
        #pragma unroll
        for (int j = 0; j < 8; ++j) {
            if (mg) { pj[j] = __builtin_ctz(mg); mg &= mg - 1; ++npg; }
            else    { pj[j] = pfirst; }
        }
        mrem = mg;
        if (npg > 4) down_group<8>(h, w2, outp, wb0, wb1, hb0, hb1, e, r0, tid, pj, npg);
        else         down_group<4>(h, w2, outp, wb0, wb1, hb0, hb1, e, r0, tid, pj, npg);
    }
}

// ---------------------------------------------------------------------------
extern "C" void kernel_launch(void* const* d_in, const int* in_sizes, int n_in,
                              void* d_out, int out_size, void* d_ws, size_t ws_size,
                              hipStream_t stream) {
    const float* x    = (const float*)d_in[0];
    const int*   eidx = (const int*)  d_in[1];
    const float* w1   = (const float*)d_in[2];
    const float* w2   = (const float*)d_in[3];
    const float* w3   = (const float*)d_in[4];
    float* out = (float*)d_out;
    float* hws = (float*)d_ws;   // [NPAIR][INTER] f32 = 360448 B

    dim3 g1(INTER / GROWS, NEXP);   // (88, 8)
    moe_gate_up<<<g1, 256, 0, stream>>>(x, eidx, w1, w3, hws);

    dim3 g2(DIM / DROWS, NEXP);     // (64, 8)
    moe_down<<<g2, 256, 0, stream>>>(hws, eidx, w2, out);
}